// Round 3
// baseline (1926.807 us; speedup 1.0000x reference)
//
#include <hip/hip_runtime.h>

#define VIEWS 360
#define NDET 736
#define NX 512
#define NY 512
#define NPIX (NX * NY)

typedef unsigned short u16;
typedef __attribute__((ext_vector_type(8))) short bf16x8;
typedef __attribute__((ext_vector_type(4))) float f32x4;

__device__ __forceinline__ u16 f2bf(float f) {
  unsigned u = __float_as_uint(f);
  return (u16)((u + 0x7fffu + ((u >> 16) & 1u)) >> 16);
}
__device__ __forceinline__ float bf2f(u16 v) {
  return __uint_as_float(((unsigned)v) << 16);
}

// async 16-B global -> LDS DMA (gfx950). LDS dest = wave-uniform base +
// lane*16 (m104); source address is per-lane.
__device__ __forceinline__ void gload_lds16(const void* g, void* l) {
  __builtin_amdgcn_global_load_lds(
      (const __attribute__((address_space(1))) void*)g,
      (__attribute__((address_space(3))) void*)l, 16, 0, 0);
}

// ---------------------------------------------------------------------------
// Linear layer, 4 views/block: out[v,d] = relu(b[d] + sum_k in[v,k] * w[d,k])
// x rows staged in LDS; each thread owns 3 d-rows x 4 views -> w traffic /4.
// ---------------------------------------------------------------------------
__global__ __launch_bounds__(256) void linear_relu4_kernel(
    const float* __restrict__ in, const float* __restrict__ w,
    const float* __restrict__ b, float* __restrict__ out) {
  __shared__ __align__(16) float xin[4][NDET];
  const int v0 = blockIdx.x * 4;
  const int t = threadIdx.x;
  for (int k = t; k < 4 * (NDET / 4); k += 256) {
    const int row = k / (NDET / 4), c4 = k % (NDET / 4);
    ((float4*)xin[row])[c4] = ((const float4*)(in + (size_t)(v0 + row) * NDET))[c4];
  }
  __syncthreads();

  const bool has2 = (t < NDET - 512);  // t < 224
  const float4* w0 = (const float4*)(w + (size_t)t * NDET);
  const float4* w1 = (const float4*)(w + (size_t)(t + 256) * NDET);
  const float4* w2 = (const float4*)(w + (size_t)(has2 ? t + 512 : t) * NDET);

  float acc[3][4];
#pragma unroll
  for (int j = 0; j < 3; ++j)
#pragma unroll
    for (int v = 0; v < 4; ++v) acc[j][v] = 0.f;

#pragma unroll 2
  for (int k = 0; k < NDET / 4; ++k) {
    float4 xv0 = ((const float4*)xin[0])[k];
    float4 xv1 = ((const float4*)xin[1])[k];
    float4 xv2 = ((const float4*)xin[2])[k];
    float4 xv3 = ((const float4*)xin[3])[k];
    float4 wv;
    wv = w0[k];
    acc[0][0] = fmaf(xv0.x, wv.x, fmaf(xv0.y, wv.y, fmaf(xv0.z, wv.z, fmaf(xv0.w, wv.w, acc[0][0]))));
    acc[0][1] = fmaf(xv1.x, wv.x, fmaf(xv1.y, wv.y, fmaf(xv1.z, wv.z, fmaf(xv1.w, wv.w, acc[0][1]))));
    acc[0][2] = fmaf(xv2.x, wv.x, fmaf(xv2.y, wv.y, fmaf(xv2.z, wv.z, fmaf(xv2.w, wv.w, acc[0][2]))));
    acc[0][3] = fmaf(xv3.x, wv.x, fmaf(xv3.y, wv.y, fmaf(xv3.z, wv.z, fmaf(xv3.w, wv.w, acc[0][3]))));
    wv = w1[k];
    acc[1][0] = fmaf(xv0.x, wv.x, fmaf(xv0.y, wv.y, fmaf(xv0.z, wv.z, fmaf(xv0.w, wv.w, acc[1][0]))));
    acc[1][1] = fmaf(xv1.x, wv.x, fmaf(xv1.y, wv.y, fmaf(xv1.z, wv.z, fmaf(xv1.w, wv.w, acc[1][1]))));
    acc[1][2] = fmaf(xv2.x, wv.x, fmaf(xv2.y, wv.y, fmaf(xv2.z, wv.z, fmaf(xv2.w, wv.w, acc[1][2]))));
    acc[1][3] = fmaf(xv3.x, wv.x, fmaf(xv3.y, wv.y, fmaf(xv3.z, wv.z, fmaf(xv3.w, wv.w, acc[1][3]))));
    wv = w2[k];
    acc[2][0] = fmaf(xv0.x, wv.x, fmaf(xv0.y, wv.y, fmaf(xv0.z, wv.z, fmaf(xv0.w, wv.w, acc[2][0]))));
    acc[2][1] = fmaf(xv1.x, wv.x, fmaf(xv1.y, wv.y, fmaf(xv1.z, wv.z, fmaf(xv1.w, wv.w, acc[2][1]))));
    acc[2][2] = fmaf(xv2.x, wv.x, fmaf(xv2.y, wv.y, fmaf(xv2.z, wv.z, fmaf(xv2.w, wv.w, acc[2][2]))));
    acc[2][3] = fmaf(xv3.x, wv.x, fmaf(xv3.y, wv.y, fmaf(xv3.z, wv.z, fmaf(xv3.w, wv.w, acc[2][3]))));
  }

  const float b0 = b[t], b1 = b[t + 256];
  const float b2v = has2 ? b[t + 512] : 0.f;
#pragma unroll
  for (int v = 0; v < 4; ++v) {
    float* o = out + (size_t)(v0 + v) * NDET;
    o[t] = fmaxf(acc[0][v] + b0, 0.f);
    o[t + 256] = fmaxf(acc[1][v] + b1, 0.f);
    if (has2) o[t + 512] = fmaxf(acc[2][v] + b2v, 0.f);
  }
}

// ---------------------------------------------------------------------------
// Backprojection: thread-owns-pixel + idx coalesced via LDS staging of
// 72-view chunks. Row pad 77 dwords -> conflict-free LDS reads.
// ---------------------------------------------------------------------------
__global__ __launch_bounds__(256) void backproj_kernel(
    const float* __restrict__ sino, const int* __restrict__ idx,
    float* __restrict__ img) {
  __shared__ int lidx[256 * 77];
  const int t = threadIdx.x;
  const int p_base = blockIdx.x * 256;

  float a0 = 0.f, a1 = 0.f, a2 = 0.f, a3 = 0.f;

#pragma unroll 1
  for (int c = 0; c < 5; ++c) {
    if (c) __syncthreads();
#pragma unroll
    for (int k = 0; k < 18; ++k) {
      const int f = k * 256 + t;
      const int row = f / 18, col4 = f % 18;
      int4 v = *(const int4*)&idx[(size_t)(p_base + row) * VIEWS + c * 72 +
                                  col4 * 4];
      int* dst = &lidx[row * 77 + col4 * 4];
      dst[0] = v.x; dst[1] = v.y; dst[2] = v.z; dst[3] = v.w;
    }
    __syncthreads();
    const int* myrow = &lidx[t * 77];
#pragma unroll
    for (int j = 0; j < 72; j += 4) {
      a0 += sino[myrow[j + 0]];
      a1 += sino[myrow[j + 1]];
      a2 += sino[myrow[j + 2]];
      a3 += sino[myrow[j + 3]];
    }
  }

  const int p = p_base + t;
  const int ix = p >> 9, iy = p & 511;
  img[(NX - 1 - ix) * NY + (NY - 1 - iy)] =
      ((a0 + a1) + (a2 + a3)) * 0.00872665f;  // END_ANGLE / (2*VIEWS)
}

// ---------------------------------------------------------------------------
// fp32 3x3 neighborhood load (zero pad), single plane
// ---------------------------------------------------------------------------
__device__ __forceinline__ void load9(const float* __restrict__ base, int gx,
                                      int gy, float v[9]) {
  const bool xm = gx > 0, xp = gx < NX - 1, ym = gy > 0, yp = gy < NY - 1;
  const float* c = base + gy * NX + gx;
  v[0] = (ym && xm) ? c[-NX - 1] : 0.f;
  v[1] = (ym)       ? c[-NX]     : 0.f;
  v[2] = (ym && xp) ? c[-NX + 1] : 0.f;
  v[3] = (xm)       ? c[-1]      : 0.f;
  v[4] =               c[0];
  v[5] = (xp)       ? c[1]       : 0.f;
  v[6] = (yp && xm) ? c[NX - 1]  : 0.f;
  v[7] = (yp)       ? c[NX]      : 0.f;
  v[8] = (yp && xp) ? c[NX + 1]  : 0.f;
}

__device__ __forceinline__ float dot9(float a, const float v[9],
                                      const float* __restrict__ w) {
  a = fmaf(v[0], w[0], a);
  a = fmaf(v[1], w[1], a);
  a = fmaf(v[2], w[2], a);
  a = fmaf(v[3], w[3], a);
  a = fmaf(v[4], w[4], a);
  a = fmaf(v[5], w[5], a);
  a = fmaf(v[6], w[6], a);
  a = fmaf(v[7], w[7], a);
  a = fmaf(v[8], w[8], a);
  return a;
}

// ---------------------------------------------------------------------------
// conv_in: 1 -> 64 ch, fp32 plane in -> fp32 trunk (yf) + bf16 shadow (ybf).
// ---------------------------------------------------------------------------
__global__ __launch_bounds__(256) void conv_in_kernel(
    const float* __restrict__ in, const float* __restrict__ w,
    const float* __restrict__ b, float* __restrict__ outf,
    u16* __restrict__ outb) {
  const int p = blockIdx.x * 256 + threadIdx.x;
  const int gx = p & (NX - 1), gy = p >> 9;
  float v[9];
  load9(in, gx, gy, v);
  float4* of = (float4*)(outf + (size_t)p * 64);
  uint4* ob = (uint4*)(outb + (size_t)p * 64);
#pragma unroll
  for (int oq = 0; oq < 8; ++oq) {
    float f[8];
#pragma unroll
    for (int c = 0; c < 8; ++c)
      f[c] = fmaxf(dot9(b[oq * 8 + c], v, w + (oq * 8 + c) * 9), 0.f);
    of[oq * 2 + 0] = (float4){f[0], f[1], f[2], f[3]};
    of[oq * 2 + 1] = (float4){f[4], f[5], f[6], f[7]};
    uint4 pk;
    pk.x = (unsigned)f2bf(f[0]) | ((unsigned)f2bf(f[1]) << 16);
    pk.y = (unsigned)f2bf(f[2]) | ((unsigned)f2bf(f[3]) << 16);
    pk.z = (unsigned)f2bf(f[4]) | ((unsigned)f2bf(f[5]) << 16);
    pk.w = (unsigned)f2bf(f[6]) | ((unsigned)f2bf(f[7]) << 16);
    ob[oq] = pk;
  }
}

// ---------------------------------------------------------------------------
// Weight prep -> per-step wave-contiguous layout, kb-MAJOR step order
// (s = kb*9 + tap). Also zeroes the 32-u16 pad region after wR (OOB halo
// source for conv64's global_load_lds staging).
// wR[li][s][lane=kg*16+n][mf][j] = W[li][oc=mf*16+n][ic=kb*32+kg*8+j][tap]
// ---------------------------------------------------------------------------
__global__ __launch_bounds__(256) void prep_weights_kernel(
    const float* __restrict__ bw1, const float* __restrict__ bw2,
    u16* __restrict__ wR) {
  const int g = blockIdx.x * 256 + threadIdx.x;
  if (g >= 22 * 36864) return;
  if (g < 32) wR[22 * 36864 + g] = 0;  // zero pad for OOB staging
  const int li = g / 36864, r1 = g % 36864;
  const int s = r1 / 2048, r2 = r1 % 2048;
  const int lane = r2 / 32, r3 = r2 % 32;
  const int mf = r3 / 8, j = r3 % 8;
  const int kb = s / 9, tap = s % 9;  // kb-major step order
  const int kg = lane >> 4, n = lane & 15;
  const int oc = mf * 16 + n;
  const int ic = kb * 32 + kg * 8 + j;
  const float* src = (li < 11) ? bw1 + li * 36864 : bw2 + (li - 11) * 36864;
  wR[g] = f2bf(src[(oc * 64 + ic) * 9 + tap]);
}

// ---------------------------------------------------------------------------
// conv64 MFMA implicit GEMM, NHWC bf16 in. M=64 oc, N=64x*4y, K=576.
// K-SPLIT staging via global_load_lds (16 B DMA): LDS holds one 32-ch half
// [r=6][xi=66][4 chunks] = 25.3 KB -> 4 blocks/CU (256,4). Grid 1024 =
// single fully-resident round, no tail.
// Swizzle on the SOURCE (rule #21): LDS written linearly in lane order;
// lane covering slot j of pixel x66 fetches chunk j ^ ((x66>>1)&3) -- a
// permutation inside the pixel's 64-B line, so coalescing is preserved.
// Read side: slot = kg ^ ((x66>>1)&3) (unchanged, 2-way max = free).
// OOB halo lanes source from a zeroed 32-u16 pad (zpad).
// Outputs: bf16 (outb) always; fp32 trunk (outf) when DUALOUT.
// Residual (ADDRES) read fp32 -> numerics bit-identical to the fp32-trunk
// config (bf16 rounding happens once, at write, = round-1's staging f2bf).
// ---------------------------------------------------------------------------
template <int ADDRES, int DUALOUT>
__global__ __launch_bounds__(256, 4) void conv64_mfma(
    const u16* __restrict__ in_, const u16* __restrict__ wA,
    const float* __restrict__ bias, const float* __restrict__ res,
    u16* __restrict__ outb, float* __restrict__ outf,
    const u16* __restrict__ zpad) {
  __shared__ __align__(16) u16 lds[6 * 66 * 32];  // 25,344 B
  const int xb = (blockIdx.x & 7) * 64;
  const int yb = (int)(blockIdx.x >> 3) * 4;
  const int tid = threadIdx.x;
  const int wv = tid >> 6;
  const int lane = tid & 63;
  const int n = lane & 15;
  const int kg = lane >> 4;

  f32x4 acc[4][4];
#pragma unroll
  for (int i = 0; i < 4; ++i)
#pragma unroll
    for (int j = 0; j < 4; ++j) acc[i][j] = (f32x4){0.f, 0.f, 0.f, 0.f};

#pragma unroll 1
  for (int kb = 0; kb < 2; ++kb) {
    if (kb) __syncthreads();  // drain reads of previous half before overwrite
    // stage one 32-ch half: 1584 x 16 B via global_load_lds, linear LDS dest
#pragma unroll
    for (int it = 0; it < 7; ++it) {
      const int g = it * 256 + tid;
      if (it < 6 || g < 1584) {
        const int j = g & 3;          // LDS slot within 64-B pixel group
        const int xr = g >> 2;        // 0..395 = r*66 + x66
        const int x66 = xr % 66;
        const int r = xr / 66;
        const int y = yb - 1 + r;
        const int x = xb - 1 + x66;
        const int icq = j ^ ((x66 >> 1) & 3);  // source chunk (pre-swizzle)
        const u16* src = zpad;
        if ((unsigned)y < 512u && (unsigned)x < 512u)
          src = in_ + ((size_t)((y << 9) + x)) * 64 + kb * 32 + icq * 8;
        gload_lds16(src, &lds[(size_t)(g & ~63) * 8]);
      }
    }
    __syncthreads();

#pragma unroll 3
    for (int tap = 0; tap < 9; ++tap) {
      const int s = kb * 9 + tap;
      bf16x8 av[4];
#pragma unroll
      for (int mf = 0; mf < 4; ++mf)
        av[mf] = *(const bf16x8*)&wA[((size_t)s * 64 + lane) * 32 + mf * 8];

      const int r = wv + tap / 3;
      const int dxp1 = tap % 3;

      bf16x8 bfr[4];
#pragma unroll
      for (int nf = 0; nf < 4; ++nf) {
        const int xi = dxp1 + nf * 16 + n;
        const int slot = kg ^ ((xi >> 1) & 3);
        bfr[nf] = *(const bf16x8*)&lds[((r * 66 + xi) * 4 + slot) * 8];
      }
#pragma unroll
      for (int mf = 0; mf < 4; ++mf)
#pragma unroll
        for (int nf = 0; nf < 4; ++nf)
          acc[mf][nf] = __builtin_amdgcn_mfma_f32_16x16x32_bf16(
              av[mf], bfr[nf], acc[mf][nf], 0, 0, 0);
    }
  }

  const int y = yb + wv;
#pragma unroll
  for (int mf = 0; mf < 4; ++mf) {
    const float4 bv = *(const float4*)&bias[mf * 16 + kg * 4];
#pragma unroll
    for (int nf = 0; nf < 4; ++nf) {
      const int x = xb + nf * 16 + n;
      const size_t base = ((size_t)((y << 9) + x)) * 64 + mf * 16 + kg * 4;
      float v0 = acc[mf][nf][0] + bv.x;
      float v1 = acc[mf][nf][1] + bv.y;
      float v2 = acc[mf][nf][2] + bv.z;
      float v3 = acc[mf][nf][3] + bv.w;
      if (ADDRES) {
        float4 rr = *(const float4*)&res[base];
        v0 += rr.x; v1 += rr.y; v2 += rr.z; v3 += rr.w;
      }
      v0 = fmaxf(v0, 0.f); v1 = fmaxf(v1, 0.f);
      v2 = fmaxf(v2, 0.f); v3 = fmaxf(v3, 0.f);
      uint2 pk;
      pk.x = (unsigned)f2bf(v0) | ((unsigned)f2bf(v1) << 16);
      pk.y = (unsigned)f2bf(v2) | ((unsigned)f2bf(v3) << 16);
      *(uint2*)&outb[base] = pk;
      if (DUALOUT) {
        *(float4*)&outf[base] = (float4){v0, v1, v2, v3};
      }
    }
  }
}

// ---------------------------------------------------------------------------
// conv_out: 64 -> 1, fp32 NHWC trunk in (float4 loads), fp32 plane out.
// ---------------------------------------------------------------------------
__global__ __launch_bounds__(256) void conv_out_kernel(
    const float* __restrict__ in, const float* __restrict__ w,
    const float* __restrict__ b, float* __restrict__ out) {
  const int p = blockIdx.x * 256 + threadIdx.x;
  const int gx = p & (NX - 1), gy = p >> 9;
  float a = b[0];
#pragma unroll
  for (int ty = 0; ty < 3; ++ty) {
#pragma unroll
    for (int tx = 0; tx < 3; ++tx) {
      const int yy = gy + ty - 1, xx = gx + tx - 1;
      if ((unsigned)yy < 512u && (unsigned)xx < 512u) {
        const float4* q = (const float4*)(in + ((size_t)((yy << 9) + xx)) * 64);
        const int tap = ty * 3 + tx;
#pragma unroll
        for (int i = 0; i < 16; ++i) {
          float4 d = q[i];
          a = fmaf(d.x, w[(i * 4 + 0) * 9 + tap], a);
          a = fmaf(d.y, w[(i * 4 + 1) * 9 + tap], a);
          a = fmaf(d.z, w[(i * 4 + 2) * 9 + tap], a);
          a = fmaf(d.w, w[(i * 4 + 3) * 9 + tap], a);
        }
      }
    }
  }
  out[p] = a;
}

// ---------------------------------------------------------------------------
extern "C" void kernel_launch(void* const* d_in, const int* in_sizes, int n_in,
                              void* d_out, int out_size, void* d_ws,
                              size_t ws_size, hipStream_t stream) {
  const float* x      = (const float*)d_in[0];
  const int*   indices= (const int*)d_in[1];
  const float* w1     = (const float*)d_in[2];
  const float* b1     = (const float*)d_in[3];
  const float* w2     = (const float*)d_in[4];
  const float* b2     = (const float*)d_in[5];
  const float* cin_w  = (const float*)d_in[6];
  const float* cin_b  = (const float*)d_in[7];
  const float* bw1    = (const float*)d_in[8];
  const float* bb1    = (const float*)d_in[9];
  const float* bw2    = (const float*)d_in[10];
  const float* bb2    = (const float*)d_in[11];
  const float* cout_w = (const float*)d_in[12];
  const float* cout_b = (const float*)d_in[13];

  float* ws   = (float*)d_ws;
  float* h1   = ws;                        // 360*736 f32
  float* h2   = h1 + VIEWS * NDET;         // 360*736 f32
  float* img  = h2 + VIEWS * NDET;         // NPIX f32 (plane)
  float* yf   = img + NPIX;                // 64*NPIX f32 NHWC (exact trunk)
  u16*  ybf   = (u16*)(yf + (size_t)64 * NPIX);  // 64*NPIX bf16 shadow trunk
  u16*  zb    = ybf + (size_t)64 * NPIX;   // 64*NPIX bf16 NHWC (block mid)
  u16*  wAll  = zb + (size_t)64 * NPIX;    // 22*64*576 bf16 (step layout)
  u16*  zpad  = wAll + 22 * 36864;         // 32 u16 of zeros (OOB source)

  prep_weights_kernel<<<(22 * 36864 + 255) / 256, 256, 0, stream>>>(bw1, bw2,
                                                                    wAll);
  linear_relu4_kernel<<<VIEWS / 4, 256, 0, stream>>>(x, w1, b1, h1);
  linear_relu4_kernel<<<VIEWS / 4, 256, 0, stream>>>(h1, w2, b2, h2);
  backproj_kernel<<<NPIX / 256, 256, 0, stream>>>(h2, indices, img);
  conv_in_kernel<<<NPIX / 256, 256, 0, stream>>>(img, cin_w, cin_b, yf, ybf);

  for (int i = 0; i < 11; ++i) {
    conv64_mfma<0, 0><<<1024, 256, 0, stream>>>(
        ybf, wAll + i * 36864, bb1 + i * 64, nullptr, zb, nullptr, zpad);
    conv64_mfma<1, 1><<<1024, 256, 0, stream>>>(
        zb, wAll + (11 + i) * 36864, bb2 + i * 64, yf, ybf, yf, zpad);
  }
  conv_out_kernel<<<NPIX / 256, 256, 0, stream>>>(yf, cout_w, cout_b,
                                                  (float*)d_out);
}

// Round 4
// 1896.037 us; speedup vs baseline: 1.0162x; 1.0162x over previous
//
#include <hip/hip_runtime.h>

#define VIEWS 360
#define NDET 736
#define NX 512
#define NY 512
#define NPIX (NX * NY)

typedef unsigned short u16;
typedef __attribute__((ext_vector_type(8))) short bf16x8;
typedef __attribute__((ext_vector_type(4))) float f32x4;

__device__ __forceinline__ u16 f2bf(float f) {
  unsigned u = __float_as_uint(f);
  return (u16)((u + 0x7fffu + ((u >> 16) & 1u)) >> 16);
}

// ---------------------------------------------------------------------------
// Linear layer, 4 views/block: out[v,d] = relu(b[d] + sum_k in[v,k] * w[d,k])
// x rows staged in LDS; each thread owns 3 d-rows x 4 views -> w traffic /4.
// ---------------------------------------------------------------------------
__global__ __launch_bounds__(256) void linear_relu4_kernel(
    const float* __restrict__ in, const float* __restrict__ w,
    const float* __restrict__ b, float* __restrict__ out) {
  __shared__ __align__(16) float xin[4][NDET];
  const int v0 = blockIdx.x * 4;
  const int t = threadIdx.x;
  for (int k = t; k < 4 * (NDET / 4); k += 256) {
    const int row = k / (NDET / 4), c4 = k % (NDET / 4);
    ((float4*)xin[row])[c4] = ((const float4*)(in + (size_t)(v0 + row) * NDET))[c4];
  }
  __syncthreads();

  const bool has2 = (t < NDET - 512);  // t < 224
  const float4* w0 = (const float4*)(w + (size_t)t * NDET);
  const float4* w1 = (const float4*)(w + (size_t)(t + 256) * NDET);
  const float4* w2 = (const float4*)(w + (size_t)(has2 ? t + 512 : t) * NDET);

  float acc[3][4];
#pragma unroll
  for (int j = 0; j < 3; ++j)
#pragma unroll
    for (int v = 0; v < 4; ++v) acc[j][v] = 0.f;

#pragma unroll 2
  for (int k = 0; k < NDET / 4; ++k) {
    float4 xv0 = ((const float4*)xin[0])[k];
    float4 xv1 = ((const float4*)xin[1])[k];
    float4 xv2 = ((const float4*)xin[2])[k];
    float4 xv3 = ((const float4*)xin[3])[k];
    float4 wv;
    wv = w0[k];
    acc[0][0] = fmaf(xv0.x, wv.x, fmaf(xv0.y, wv.y, fmaf(xv0.z, wv.z, fmaf(xv0.w, wv.w, acc[0][0]))));
    acc[0][1] = fmaf(xv1.x, wv.x, fmaf(xv1.y, wv.y, fmaf(xv1.z, wv.z, fmaf(xv1.w, wv.w, acc[0][1]))));
    acc[0][2] = fmaf(xv2.x, wv.x, fmaf(xv2.y, wv.y, fmaf(xv2.z, wv.z, fmaf(xv2.w, wv.w, acc[0][2]))));
    acc[0][3] = fmaf(xv3.x, wv.x, fmaf(xv3.y, wv.y, fmaf(xv3.z, wv.z, fmaf(xv3.w, wv.w, acc[0][3]))));
    wv = w1[k];
    acc[1][0] = fmaf(xv0.x, wv.x, fmaf(xv0.y, wv.y, fmaf(xv0.z, wv.z, fmaf(xv0.w, wv.w, acc[1][0]))));
    acc[1][1] = fmaf(xv1.x, wv.x, fmaf(xv1.y, wv.y, fmaf(xv1.z, wv.z, fmaf(xv1.w, wv.w, acc[1][1]))));
    acc[1][2] = fmaf(xv2.x, wv.x, fmaf(xv2.y, wv.y, fmaf(xv2.z, wv.z, fmaf(xv2.w, wv.w, acc[1][2]))));
    acc[1][3] = fmaf(xv3.x, wv.x, fmaf(xv3.y, wv.y, fmaf(xv3.z, wv.z, fmaf(xv3.w, wv.w, acc[1][3]))));
    wv = w2[k];
    acc[2][0] = fmaf(xv0.x, wv.x, fmaf(xv0.y, wv.y, fmaf(xv0.z, wv.z, fmaf(xv0.w, wv.w, acc[2][0]))));
    acc[2][1] = fmaf(xv1.x, wv.x, fmaf(xv1.y, wv.y, fmaf(xv1.z, wv.z, fmaf(xv1.w, wv.w, acc[2][1]))));
    acc[2][2] = fmaf(xv2.x, wv.x, fmaf(xv2.y, wv.y, fmaf(xv2.z, wv.z, fmaf(xv2.w, wv.w, acc[2][2]))));
    acc[2][3] = fmaf(xv3.x, wv.x, fmaf(xv3.y, wv.y, fmaf(xv3.z, wv.z, fmaf(xv3.w, wv.w, acc[2][3]))));
  }

  const float b0 = b[t], b1 = b[t + 256];
  const float b2v = has2 ? b[t + 512] : 0.f;
#pragma unroll
  for (int v = 0; v < 4; ++v) {
    float* o = out + (size_t)(v0 + v) * NDET;
    o[t] = fmaxf(acc[0][v] + b0, 0.f);
    o[t + 256] = fmaxf(acc[1][v] + b1, 0.f);
    if (has2) o[t + 512] = fmaxf(acc[2][v] + b2v, 0.f);
  }
}

// ---------------------------------------------------------------------------
// Backprojection: thread-owns-pixel + idx coalesced via LDS staging of
// 72-view chunks. Row pad 77 dwords -> conflict-free LDS reads.
// ---------------------------------------------------------------------------
__global__ __launch_bounds__(256) void backproj_kernel(
    const float* __restrict__ sino, const int* __restrict__ idx,
    float* __restrict__ img) {
  __shared__ int lidx[256 * 77];
  const int t = threadIdx.x;
  const int p_base = blockIdx.x * 256;

  float a0 = 0.f, a1 = 0.f, a2 = 0.f, a3 = 0.f;

#pragma unroll 1
  for (int c = 0; c < 5; ++c) {
    if (c) __syncthreads();
#pragma unroll
    for (int k = 0; k < 18; ++k) {
      const int f = k * 256 + t;
      const int row = f / 18, col4 = f % 18;
      int4 v = *(const int4*)&idx[(size_t)(p_base + row) * VIEWS + c * 72 +
                                  col4 * 4];
      int* dst = &lidx[row * 77 + col4 * 4];
      dst[0] = v.x; dst[1] = v.y; dst[2] = v.z; dst[3] = v.w;
    }
    __syncthreads();
    const int* myrow = &lidx[t * 77];
#pragma unroll
    for (int j = 0; j < 72; j += 4) {
      a0 += sino[myrow[j + 0]];
      a1 += sino[myrow[j + 1]];
      a2 += sino[myrow[j + 2]];
      a3 += sino[myrow[j + 3]];
    }
  }

  const int p = p_base + t;
  const int ix = p >> 9, iy = p & 511;
  img[(NX - 1 - ix) * NY + (NY - 1 - iy)] =
      ((a0 + a1) + (a2 + a3)) * 0.00872665f;  // END_ANGLE / (2*VIEWS)
}

// ---------------------------------------------------------------------------
// fp32 3x3 neighborhood load (zero pad), single plane
// ---------------------------------------------------------------------------
__device__ __forceinline__ void load9(const float* __restrict__ base, int gx,
                                      int gy, float v[9]) {
  const bool xm = gx > 0, xp = gx < NX - 1, ym = gy > 0, yp = gy < NY - 1;
  const float* c = base + gy * NX + gx;
  v[0] = (ym && xm) ? c[-NX - 1] : 0.f;
  v[1] = (ym)       ? c[-NX]     : 0.f;
  v[2] = (ym && xp) ? c[-NX + 1] : 0.f;
  v[3] = (xm)       ? c[-1]      : 0.f;
  v[4] =               c[0];
  v[5] = (xp)       ? c[1]       : 0.f;
  v[6] = (yp && xm) ? c[NX - 1]  : 0.f;
  v[7] = (yp)       ? c[NX]      : 0.f;
  v[8] = (yp && xp) ? c[NX + 1]  : 0.f;
}

__device__ __forceinline__ float dot9(float a, const float v[9],
                                      const float* __restrict__ w) {
  a = fmaf(v[0], w[0], a);
  a = fmaf(v[1], w[1], a);
  a = fmaf(v[2], w[2], a);
  a = fmaf(v[3], w[3], a);
  a = fmaf(v[4], w[4], a);
  a = fmaf(v[5], w[5], a);
  a = fmaf(v[6], w[6], a);
  a = fmaf(v[7], w[7], a);
  a = fmaf(v[8], w[8], a);
  return a;
}

// ---------------------------------------------------------------------------
// conv_in: 1 -> 64 channels, fp32 plane in -> fp32 NHWC out, float4 stores.
// ---------------------------------------------------------------------------
__global__ __launch_bounds__(256) void conv_in_kernel(
    const float* __restrict__ in, const float* __restrict__ w,
    const float* __restrict__ b, float* __restrict__ out) {
  const int p = blockIdx.x * 256 + threadIdx.x;
  const int gx = p & (NX - 1), gy = p >> 9;
  float v[9];
  load9(in, gx, gy, v);
  float4* o = (float4*)(out + (size_t)p * 64);
#pragma unroll
  for (int oq = 0; oq < 16; ++oq) {
    float4 r;
    r.x = fmaxf(dot9(b[oq * 4 + 0], v, w + (oq * 4 + 0) * 9), 0.f);
    r.y = fmaxf(dot9(b[oq * 4 + 1], v, w + (oq * 4 + 1) * 9), 0.f);
    r.z = fmaxf(dot9(b[oq * 4 + 2], v, w + (oq * 4 + 2) * 9), 0.f);
    r.w = fmaxf(dot9(b[oq * 4 + 3], v, w + (oq * 4 + 3) * 9), 0.f);
    o[oq] = r;
  }
}

// ---------------------------------------------------------------------------
// Weight prep -> per-(step,mf)-CONTIGUOUS layout (A-load coalescing fix):
//   wR[li][s][mf][lane][j] = W[li][oc=mf*16+(lane&15)][ic=kb*32+(lane>>4)*8+j][tap]
// with s = kb*9 + tap (kb-major). A wave A-load for fixed (s,mf) now reads a
// contiguous 1 KB block (lane stride 16 B) -> 16 cache lines, fully used
// (was: stride 64 B -> 64 lines, 25% used -> 4x L2 traffic + 4x TA txns).
// ---------------------------------------------------------------------------
__global__ __launch_bounds__(256) void prep_weights_kernel(
    const float* __restrict__ bw1, const float* __restrict__ bw2,
    u16* __restrict__ wR) {
  const int g = blockIdx.x * 256 + threadIdx.x;
  if (g >= 22 * 36864) return;
  const int li = g / 36864, r1 = g % 36864;
  const int s = r1 / 2048, r2 = r1 % 2048;
  const int mf = r2 / 512, r3 = r2 % 512;
  const int lane = r3 / 8, j = r3 % 8;
  const int kb = s / 9, tap = s % 9;  // kb-major step order
  const int kg = lane >> 4, n = lane & 15;
  const int oc = mf * 16 + n;
  const int ic = kb * 32 + kg * 8 + j;
  const float* src = (li < 11) ? bw1 + li * 36864 : bw2 + (li - 11) * 36864;
  wR[g] = f2bf(src[(oc * 64 + ic) * 9 + tap]);
}

// ---------------------------------------------------------------------------
// conv64 MFMA implicit GEMM, NHWC. M=64 oc, N=64x*4y, K=576.
// K-SPLIT staging: LDS holds one 32-ch half [r=6][xi=66][4 chunks of 8ch]
// = 25.3 KB -> 4 blocks/CU (launch_bounds 256,4). Grid 1024 = single
// fully-resident round, no tail. Step order kb-major, matching prep.
// LDS swizzle: slot = chunk ^ ((xi>>1)&3) -> 2-way max on write+read (free).
// A-loads per (s,mf) are contiguous 1 KB wave reads (layout fix above).
// mfma_f32_16x16x32_bf16; C/D col=lane&15, row=(lane>>4)*4+reg (m89).
// ---------------------------------------------------------------------------
template <int IN_BF, int OUT_BF, int RELU, int ADDRES>
__global__ __launch_bounds__(256, 4) void conv64_mfma(
    const void* __restrict__ in_, const u16* __restrict__ wA,
    const float* __restrict__ bias, const float* __restrict__ res,
    void* __restrict__ out_) {
  __shared__ __align__(16) u16 lds[6 * 66 * 32];  // 25,344 B
  const int xb = (blockIdx.x & 7) * 64;
  const int yb = (int)(blockIdx.x >> 3) * 4;
  const int tid = threadIdx.x;
  const int wv = tid >> 6;
  const int lane = tid & 63;
  const int n = lane & 15;
  const int kg = lane >> 4;

  f32x4 acc[4][4];
#pragma unroll
  for (int i = 0; i < 4; ++i)
#pragma unroll
    for (int j = 0; j < 4; ++j) acc[i][j] = (f32x4){0.f, 0.f, 0.f, 0.f};

#pragma unroll 1
  for (int kb = 0; kb < 2; ++kb) {
    if (kb) __syncthreads();  // drain reads of previous half before overwrite
    // stage one 32-ch half: 6 rows x 66 xi x 4 chunks = 1584 uint4
#pragma unroll
    for (int it = 0; it < 7; ++it) {
      const int g = it * 256 + tid;
      if (g < 1584) {
        const int icq = g & 3;        // 8-ch chunk within this half
        const int xr = g >> 2;        // 0..395 = r*66 + x66
        const int x66 = xr % 66;
        const int r = xr / 66;
        const int y = yb - 1 + r;
        const int x = xb - 1 + x66;
        uint4 d = {0u, 0u, 0u, 0u};
        if ((unsigned)y < 512u && (unsigned)x < 512u) {
          const size_t gi =
              ((size_t)((y << 9) + x)) * 64 + kb * 32 + icq * 8;
          if (IN_BF) {
            d = *(const uint4*)&((const u16*)in_)[gi];
          } else {
            const float* s = &((const float*)in_)[gi];
            float4 f0 = *(const float4*)s;
            float4 f1 = *(const float4*)(s + 4);
            d.x = (unsigned)f2bf(f0.x) | ((unsigned)f2bf(f0.y) << 16);
            d.y = (unsigned)f2bf(f0.z) | ((unsigned)f2bf(f0.w) << 16);
            d.z = (unsigned)f2bf(f1.x) | ((unsigned)f2bf(f1.y) << 16);
            d.w = (unsigned)f2bf(f1.z) | ((unsigned)f2bf(f1.w) << 16);
          }
        }
        const int slot = icq ^ ((x66 >> 1) & 3);
        *(uint4*)&lds[(xr * 4 + slot) * 8] = d;
      }
    }
    __syncthreads();

#pragma unroll 3
    for (int tap = 0; tap < 9; ++tap) {
      const int s = kb * 9 + tap;
      bf16x8 av[4];
#pragma unroll
      for (int mf = 0; mf < 4; ++mf)
        av[mf] = *(const bf16x8*)&wA[(size_t)s * 2048 + mf * 512 + lane * 8];

      const int r = wv + tap / 3;
      const int dxp1 = tap % 3;

      bf16x8 bfr[4];
#pragma unroll
      for (int nf = 0; nf < 4; ++nf) {
        const int xi = dxp1 + nf * 16 + n;
        const int slot = kg ^ ((xi >> 1) & 3);
        bfr[nf] = *(const bf16x8*)&lds[((r * 66 + xi) * 4 + slot) * 8];
      }
#pragma unroll
      for (int mf = 0; mf < 4; ++mf)
#pragma unroll
        for (int nf = 0; nf < 4; ++nf)
          acc[mf][nf] = __builtin_amdgcn_mfma_f32_16x16x32_bf16(
              av[mf], bfr[nf], acc[mf][nf], 0, 0, 0);
    }
  }

  const int y = yb + wv;
#pragma unroll
  for (int mf = 0; mf < 4; ++mf) {
    const float4 bv = *(const float4*)&bias[mf * 16 + kg * 4];
#pragma unroll
    for (int nf = 0; nf < 4; ++nf) {
      const int x = xb + nf * 16 + n;
      const size_t base = ((size_t)((y << 9) + x)) * 64 + mf * 16 + kg * 4;
      float v0 = acc[mf][nf][0] + bv.x;
      float v1 = acc[mf][nf][1] + bv.y;
      float v2 = acc[mf][nf][2] + bv.z;
      float v3 = acc[mf][nf][3] + bv.w;
      if (ADDRES) {
        float4 rr = *(const float4*)&res[base];
        v0 += rr.x; v1 += rr.y; v2 += rr.z; v3 += rr.w;
      }
      if (RELU) {
        v0 = fmaxf(v0, 0.f); v1 = fmaxf(v1, 0.f);
        v2 = fmaxf(v2, 0.f); v3 = fmaxf(v3, 0.f);
      }
      if (OUT_BF) {
        uint2 pk;
        pk.x = (unsigned)f2bf(v0) | ((unsigned)f2bf(v1) << 16);
        pk.y = (unsigned)f2bf(v2) | ((unsigned)f2bf(v3) << 16);
        *(uint2*)&((u16*)out_)[base] = pk;
      } else {
        *(float4*)&((float*)out_)[base] = (float4){v0, v1, v2, v3};
      }
    }
  }
}

// ---------------------------------------------------------------------------
// conv_out: 64 -> 1, fp32 NHWC in (float4 loads), fp32 plane out.
// ---------------------------------------------------------------------------
__global__ __launch_bounds__(256) void conv_out_kernel(
    const float* __restrict__ in, const float* __restrict__ w,
    const float* __restrict__ b, float* __restrict__ out) {
  const int p = blockIdx.x * 256 + threadIdx.x;
  const int gx = p & (NX - 1), gy = p >> 9;
  float a = b[0];
#pragma unroll
  for (int ty = 0; ty < 3; ++ty) {
#pragma unroll
    for (int tx = 0; tx < 3; ++tx) {
      const int yy = gy + ty - 1, xx = gx + tx - 1;
      if ((unsigned)yy < 512u && (unsigned)xx < 512u) {
        const float4* q = (const float4*)(in + ((size_t)((yy << 9) + xx)) * 64);
        const int tap = ty * 3 + tx;
#pragma unroll
        for (int i = 0; i < 16; ++i) {
          float4 d = q[i];
          a = fmaf(d.x, w[(i * 4 + 0) * 9 + tap], a);
          a = fmaf(d.y, w[(i * 4 + 1) * 9 + tap], a);
          a = fmaf(d.z, w[(i * 4 + 2) * 9 + tap], a);
          a = fmaf(d.w, w[(i * 4 + 3) * 9 + tap], a);
        }
      }
    }
  }
  out[p] = a;
}

// ---------------------------------------------------------------------------
extern "C" void kernel_launch(void* const* d_in, const int* in_sizes, int n_in,
                              void* d_out, int out_size, void* d_ws,
                              size_t ws_size, hipStream_t stream) {
  const float* x      = (const float*)d_in[0];
  const int*   indices= (const int*)d_in[1];
  const float* w1     = (const float*)d_in[2];
  const float* b1     = (const float*)d_in[3];
  const float* w2     = (const float*)d_in[4];
  const float* b2     = (const float*)d_in[5];
  const float* cin_w  = (const float*)d_in[6];
  const float* cin_b  = (const float*)d_in[7];
  const float* bw1    = (const float*)d_in[8];
  const float* bb1    = (const float*)d_in[9];
  const float* bw2    = (const float*)d_in[10];
  const float* bb2    = (const float*)d_in[11];
  const float* cout_w = (const float*)d_in[12];
  const float* cout_b = (const float*)d_in[13];

  float* ws   = (float*)d_ws;
  float* h1   = ws;                      // 360*736 f32
  float* h2   = h1 + VIEWS * NDET;       // 360*736 f32
  float* img  = h2 + VIEWS * NDET;       // NPIX f32 (plane)
  float* yf   = img + NPIX;              // 64*NPIX f32 NHWC (residual stream)
  u16*  zb    = (u16*)(yf + (size_t)64 * NPIX);  // 64*NPIX bf16 NHWC
  u16*  wAll  = zb + (size_t)64 * NPIX;  // 22*64*576 bf16 (step,mf layout)

  prep_weights_kernel<<<(22 * 36864 + 255) / 256, 256, 0, stream>>>(bw1, bw2,
                                                                    wAll);
  linear_relu4_kernel<<<VIEWS / 4, 256, 0, stream>>>(x, w1, b1, h1);
  linear_relu4_kernel<<<VIEWS / 4, 256, 0, stream>>>(h1, w2, b2, h2);
  backproj_kernel<<<NPIX / 256, 256, 0, stream>>>(h2, indices, img);
  conv_in_kernel<<<NPIX / 256, 256, 0, stream>>>(img, cin_w, cin_b, yf);

  for (int i = 0; i < 11; ++i) {
    conv64_mfma<0, 1, 1, 0><<<1024, 256, 0, stream>>>(
        yf, wAll + i * 36864, bb1 + i * 64, nullptr, zb);
    conv64_mfma<1, 0, 1, 1><<<1024, 256, 0, stream>>>(
        zb, wAll + (11 + i) * 36864, bb2 + i * 64, yf, yf);
  }
  conv_out_kernel<<<NPIX / 256, 256, 0, stream>>>(yf, cout_w, cout_b,
                                                  (float*)d_out);
}

// Round 5
// 1848.922 us; speedup vs baseline: 1.0421x; 1.0255x over previous
//
#include <hip/hip_runtime.h>

#define VIEWS 360
#define NDET 736
#define NX 512
#define NY 512
#define NPIX (NX * NY)

typedef unsigned short u16;
typedef __attribute__((ext_vector_type(8))) short bf16x8;
typedef __attribute__((ext_vector_type(4))) float f32x4;

__device__ __forceinline__ u16 f2bf(float f) {
  unsigned u = __float_as_uint(f);
  return (u16)((u + 0x7fffu + ((u >> 16) & 1u)) >> 16);
}

// ---------------------------------------------------------------------------
// Linear layer, 4 views/block: out[v,d] = relu(b[d] + sum_k in[v,k] * w[d,k])
// x rows staged in LDS; each thread owns 3 d-rows x 4 views -> w traffic /4.
// ---------------------------------------------------------------------------
__global__ __launch_bounds__(256) void linear_relu4_kernel(
    const float* __restrict__ in, const float* __restrict__ w,
    const float* __restrict__ b, float* __restrict__ out) {
  __shared__ __align__(16) float xin[4][NDET];
  const int v0 = blockIdx.x * 4;
  const int t = threadIdx.x;
  for (int k = t; k < 4 * (NDET / 4); k += 256) {
    const int row = k / (NDET / 4), c4 = k % (NDET / 4);
    ((float4*)xin[row])[c4] = ((const float4*)(in + (size_t)(v0 + row) * NDET))[c4];
  }
  __syncthreads();

  const bool has2 = (t < NDET - 512);  // t < 224
  const float4* w0 = (const float4*)(w + (size_t)t * NDET);
  const float4* w1 = (const float4*)(w + (size_t)(t + 256) * NDET);
  const float4* w2 = (const float4*)(w + (size_t)(has2 ? t + 512 : t) * NDET);

  float acc[3][4];
#pragma unroll
  for (int j = 0; j < 3; ++j)
#pragma unroll
    for (int v = 0; v < 4; ++v) acc[j][v] = 0.f;

#pragma unroll 2
  for (int k = 0; k < NDET / 4; ++k) {
    float4 xv0 = ((const float4*)xin[0])[k];
    float4 xv1 = ((const float4*)xin[1])[k];
    float4 xv2 = ((const float4*)xin[2])[k];
    float4 xv3 = ((const float4*)xin[3])[k];
    float4 wv;
    wv = w0[k];
    acc[0][0] = fmaf(xv0.x, wv.x, fmaf(xv0.y, wv.y, fmaf(xv0.z, wv.z, fmaf(xv0.w, wv.w, acc[0][0]))));
    acc[0][1] = fmaf(xv1.x, wv.x, fmaf(xv1.y, wv.y, fmaf(xv1.z, wv.z, fmaf(xv1.w, wv.w, acc[0][1]))));
    acc[0][2] = fmaf(xv2.x, wv.x, fmaf(xv2.y, wv.y, fmaf(xv2.z, wv.z, fmaf(xv2.w, wv.w, acc[0][2]))));
    acc[0][3] = fmaf(xv3.x, wv.x, fmaf(xv3.y, wv.y, fmaf(xv3.z, wv.z, fmaf(xv3.w, wv.w, acc[0][3]))));
    wv = w1[k];
    acc[1][0] = fmaf(xv0.x, wv.x, fmaf(xv0.y, wv.y, fmaf(xv0.z, wv.z, fmaf(xv0.w, wv.w, acc[1][0]))));
    acc[1][1] = fmaf(xv1.x, wv.x, fmaf(xv1.y, wv.y, fmaf(xv1.z, wv.z, fmaf(xv1.w, wv.w, acc[1][1]))));
    acc[1][2] = fmaf(xv2.x, wv.x, fmaf(xv2.y, wv.y, fmaf(xv2.z, wv.z, fmaf(xv2.w, wv.w, acc[1][2]))));
    acc[1][3] = fmaf(xv3.x, wv.x, fmaf(xv3.y, wv.y, fmaf(xv3.z, wv.z, fmaf(xv3.w, wv.w, acc[1][3]))));
    wv = w2[k];
    acc[2][0] = fmaf(xv0.x, wv.x, fmaf(xv0.y, wv.y, fmaf(xv0.z, wv.z, fmaf(xv0.w, wv.w, acc[2][0]))));
    acc[2][1] = fmaf(xv1.x, wv.x, fmaf(xv1.y, wv.y, fmaf(xv1.z, wv.z, fmaf(xv1.w, wv.w, acc[2][1]))));
    acc[2][2] = fmaf(xv2.x, wv.x, fmaf(xv2.y, wv.y, fmaf(xv2.z, wv.z, fmaf(xv2.w, wv.w, acc[2][2]))));
    acc[2][3] = fmaf(xv3.x, wv.x, fmaf(xv3.y, wv.y, fmaf(xv3.z, wv.z, fmaf(xv3.w, wv.w, acc[2][3]))));
  }

  const float b0 = b[t], b1 = b[t + 256];
  const float b2v = has2 ? b[t + 512] : 0.f;
#pragma unroll
  for (int v = 0; v < 4; ++v) {
    float* o = out + (size_t)(v0 + v) * NDET;
    o[t] = fmaxf(acc[0][v] + b0, 0.f);
    o[t + 256] = fmaxf(acc[1][v] + b1, 0.f);
    if (has2) o[t + 512] = fmaxf(acc[2][v] + b2v, 0.f);
  }
}

// ---------------------------------------------------------------------------
// Backprojection: thread-owns-pixel + idx coalesced via LDS staging of
// 72-view chunks. Row pad 77 dwords -> conflict-free LDS reads.
// ---------------------------------------------------------------------------
__global__ __launch_bounds__(256) void backproj_kernel(
    const float* __restrict__ sino, const int* __restrict__ idx,
    float* __restrict__ img) {
  __shared__ int lidx[256 * 77];
  const int t = threadIdx.x;
  const int p_base = blockIdx.x * 256;

  float a0 = 0.f, a1 = 0.f, a2 = 0.f, a3 = 0.f;

#pragma unroll 1
  for (int c = 0; c < 5; ++c) {
    if (c) __syncthreads();
#pragma unroll
    for (int k = 0; k < 18; ++k) {
      const int f = k * 256 + t;
      const int row = f / 18, col4 = f % 18;
      int4 v = *(const int4*)&idx[(size_t)(p_base + row) * VIEWS + c * 72 +
                                  col4 * 4];
      int* dst = &lidx[row * 77 + col4 * 4];
      dst[0] = v.x; dst[1] = v.y; dst[2] = v.z; dst[3] = v.w;
    }
    __syncthreads();
    const int* myrow = &lidx[t * 77];
#pragma unroll
    for (int j = 0; j < 72; j += 4) {
      a0 += sino[myrow[j + 0]];
      a1 += sino[myrow[j + 1]];
      a2 += sino[myrow[j + 2]];
      a3 += sino[myrow[j + 3]];
    }
  }

  const int p = p_base + t;
  const int ix = p >> 9, iy = p & 511;
  img[(NX - 1 - ix) * NY + (NY - 1 - iy)] =
      ((a0 + a1) + (a2 + a3)) * 0.00872665f;  // END_ANGLE / (2*VIEWS)
}

// ---------------------------------------------------------------------------
// fp32 3x3 neighborhood load (zero pad), single plane
// ---------------------------------------------------------------------------
__device__ __forceinline__ void load9(const float* __restrict__ base, int gx,
                                      int gy, float v[9]) {
  const bool xm = gx > 0, xp = gx < NX - 1, ym = gy > 0, yp = gy < NY - 1;
  const float* c = base + gy * NX + gx;
  v[0] = (ym && xm) ? c[-NX - 1] : 0.f;
  v[1] = (ym)       ? c[-NX]     : 0.f;
  v[2] = (ym && xp) ? c[-NX + 1] : 0.f;
  v[3] = (xm)       ? c[-1]      : 0.f;
  v[4] =               c[0];
  v[5] = (xp)       ? c[1]       : 0.f;
  v[6] = (yp && xm) ? c[NX - 1]  : 0.f;
  v[7] = (yp)       ? c[NX]      : 0.f;
  v[8] = (yp && xp) ? c[NX + 1]  : 0.f;
}

__device__ __forceinline__ float dot9(float a, const float v[9],
                                      const float* __restrict__ w) {
  a = fmaf(v[0], w[0], a);
  a = fmaf(v[1], w[1], a);
  a = fmaf(v[2], w[2], a);
  a = fmaf(v[3], w[3], a);
  a = fmaf(v[4], w[4], a);
  a = fmaf(v[5], w[5], a);
  a = fmaf(v[6], w[6], a);
  a = fmaf(v[7], w[7], a);
  a = fmaf(v[8], w[8], a);
  return a;
}

// ---------------------------------------------------------------------------
// conv_in: 1 -> 64 channels, fp32 plane in -> fp32 NHWC out, float4 stores.
// ---------------------------------------------------------------------------
__global__ __launch_bounds__(256) void conv_in_kernel(
    const float* __restrict__ in, const float* __restrict__ w,
    const float* __restrict__ b, float* __restrict__ out) {
  const int p = blockIdx.x * 256 + threadIdx.x;
  const int gx = p & (NX - 1), gy = p >> 9;
  float v[9];
  load9(in, gx, gy, v);
  float4* o = (float4*)(out + (size_t)p * 64);
#pragma unroll
  for (int oq = 0; oq < 16; ++oq) {
    float4 r;
    r.x = fmaxf(dot9(b[oq * 4 + 0], v, w + (oq * 4 + 0) * 9), 0.f);
    r.y = fmaxf(dot9(b[oq * 4 + 1], v, w + (oq * 4 + 1) * 9), 0.f);
    r.z = fmaxf(dot9(b[oq * 4 + 2], v, w + (oq * 4 + 2) * 9), 0.f);
    r.w = fmaxf(dot9(b[oq * 4 + 3], v, w + (oq * 4 + 3) * 9), 0.f);
    o[oq] = r;
  }
}

// ---------------------------------------------------------------------------
// Weight prep -> per-(step,mf)-contiguous layout:
//   wR[li][s][mf][lane][j] = W[li][oc=mf*16+(lane&15)][ic=kb*32+(lane>>4)*8+j][tap]
// with s = kb*9 + tap (kb-major).
// ---------------------------------------------------------------------------
__global__ __launch_bounds__(256) void prep_weights_kernel(
    const float* __restrict__ bw1, const float* __restrict__ bw2,
    u16* __restrict__ wR) {
  const int g = blockIdx.x * 256 + threadIdx.x;
  if (g >= 22 * 36864) return;
  const int li = g / 36864, r1 = g % 36864;
  const int s = r1 / 2048, r2 = r1 % 2048;
  const int mf = r2 / 512, r3 = r2 % 512;
  const int lane = r3 / 8, j = r3 % 8;
  const int kb = s / 9, tap = s % 9;  // kb-major step order
  const int kg = lane >> 4, n = lane & 15;
  const int oc = mf * 16 + n;
  const int ic = kb * 32 + kg * 8 + j;
  const float* src = (li < 11) ? bw1 + li * 36864 : bw2 + (li - 11) * 36864;
  wR[g] = f2bf(src[(oc * 64 + ic) * 9 + tap]);
}

// ---------------------------------------------------------------------------
// conv64 MFMA implicit GEMM, NHWC. M=64 oc, N=64x*4y, K=576.
// K-SPLIT staging: LDS holds one 32-ch half [r=6][xi=66][4 chunks of 8ch]
// = 25.3 KB -> 4 blocks/CU (launch_bounds 256,4). Grid 1024 = single
// fully-resident round, no tail. Step order kb-major, matching prep.
// LDS swizzle: slot = chunk ^ ((xi>>1)&3) -> 2-way max on write+read (free).
// EPILOGUE (new): acc -> LDS transpose (reuses staging buffer, padded rows,
// <=2-way banks) -> linear readback where 4 consecutive lanes cover one
// pixel's full 64-B channel block -> every global store (and the conv2
// residual gather) is a FULL cache line. Replaces the per-lane 128/256-B
// stride scatter (64 partial-line txns per wave-store, 8x dense count).
// Arithmetic order unchanged (bias -> [res] -> relu) => bit-identical.
// mfma_f32_16x16x32_bf16; C/D col=lane&15, row=(lane>>4)*4+reg (m89).
// ---------------------------------------------------------------------------
template <int IN_BF, int OUT_BF, int RELU, int ADDRES>
__global__ __launch_bounds__(256, 4) void conv64_mfma(
    const void* __restrict__ in_, const u16* __restrict__ wA,
    const float* __restrict__ bias, const float* __restrict__ res,
    void* __restrict__ out_) {
  __shared__ __align__(16) u16 lds[6 * 66 * 32];  // 25,344 B (staging & epi)
  const int xb = (blockIdx.x & 7) * 64;
  const int yb = (int)(blockIdx.x >> 3) * 4;
  const int tid = threadIdx.x;
  const int wv = tid >> 6;
  const int lane = tid & 63;
  const int n = lane & 15;
  const int kg = lane >> 4;

  f32x4 acc[4][4];
#pragma unroll
  for (int i = 0; i < 4; ++i)
#pragma unroll
    for (int j = 0; j < 4; ++j) acc[i][j] = (f32x4){0.f, 0.f, 0.f, 0.f};

#pragma unroll 1
  for (int kb = 0; kb < 2; ++kb) {
    if (kb) __syncthreads();  // drain reads of previous half before overwrite
    // stage one 32-ch half: 6 rows x 66 xi x 4 chunks = 1584 uint4
#pragma unroll
    for (int it = 0; it < 7; ++it) {
      const int g = it * 256 + tid;
      if (g < 1584) {
        const int icq = g & 3;        // 8-ch chunk within this half
        const int xr = g >> 2;        // 0..395 = r*66 + x66
        const int x66 = xr % 66;
        const int r = xr / 66;
        const int y = yb - 1 + r;
        const int x = xb - 1 + x66;
        uint4 d = {0u, 0u, 0u, 0u};
        if ((unsigned)y < 512u && (unsigned)x < 512u) {
          const size_t gi =
              ((size_t)((y << 9) + x)) * 64 + kb * 32 + icq * 8;
          if (IN_BF) {
            d = *(const uint4*)&((const u16*)in_)[gi];
          } else {
            const float* s = &((const float*)in_)[gi];
            float4 f0 = *(const float4*)s;
            float4 f1 = *(const float4*)(s + 4);
            d.x = (unsigned)f2bf(f0.x) | ((unsigned)f2bf(f0.y) << 16);
            d.y = (unsigned)f2bf(f0.z) | ((unsigned)f2bf(f0.w) << 16);
            d.z = (unsigned)f2bf(f1.x) | ((unsigned)f2bf(f1.y) << 16);
            d.w = (unsigned)f2bf(f1.z) | ((unsigned)f2bf(f1.w) << 16);
          }
        }
        const int slot = icq ^ ((x66 >> 1) & 3);
        *(uint4*)&lds[(xr * 4 + slot) * 8] = d;
      }
    }
    __syncthreads();

#pragma unroll 3
    for (int tap = 0; tap < 9; ++tap) {
      const int s = kb * 9 + tap;
      bf16x8 av[4];
#pragma unroll
      for (int mf = 0; mf < 4; ++mf)
        av[mf] = *(const bf16x8*)&wA[(size_t)s * 2048 + mf * 512 + lane * 8];

      const int r = wv + tap / 3;
      const int dxp1 = tap % 3;

      bf16x8 bfr[4];
#pragma unroll
      for (int nf = 0; nf < 4; ++nf) {
        const int xi = dxp1 + nf * 16 + n;
        const int slot = kg ^ ((xi >> 1) & 3);
        bfr[nf] = *(const bf16x8*)&lds[((r * 66 + xi) * 4 + slot) * 8];
      }
#pragma unroll
      for (int mf = 0; mf < 4; ++mf)
#pragma unroll
        for (int nf = 0; nf < 4; ++nf)
          acc[mf][nf] = __builtin_amdgcn_mfma_f32_16x16x32_bf16(
              av[mf], bfr[nf], acc[mf][nf], 0, 0, 0);
    }
  }

  // ---- epilogue via LDS transpose -> dense full-line global accesses ----
  if (OUT_BF) {
    // bf16 out: two phases of 32 ch (mf-pair). LDS view [4y][64x][40] u16
    // (row pad 40 -> 80 B: 16B-aligned rows, <=2-way banks).
#pragma unroll
    for (int mp = 0; mp < 2; ++mp) {
      __syncthreads();
#pragma unroll
      for (int mh = 0; mh < 2; ++mh) {
        const int mf = mp * 2 + mh;
        const float4 bv = *(const float4*)&bias[mf * 16 + kg * 4];
#pragma unroll
        for (int nf = 0; nf < 4; ++nf) {
          float v0 = acc[mf][nf][0] + bv.x;
          float v1 = acc[mf][nf][1] + bv.y;
          float v2 = acc[mf][nf][2] + bv.z;
          float v3 = acc[mf][nf][3] + bv.w;
          if (RELU) {
            v0 = fmaxf(v0, 0.f); v1 = fmaxf(v1, 0.f);
            v2 = fmaxf(v2, 0.f); v3 = fmaxf(v3, 0.f);
          }
          uint2 pk;
          pk.x = (unsigned)f2bf(v0) | ((unsigned)f2bf(v1) << 16);
          pk.y = (unsigned)f2bf(v2) | ((unsigned)f2bf(v3) << 16);
          *(uint2*)&lds[(wv * 64 + nf * 16 + n) * 40 + mh * 16 + kg * 4] = pk;
        }
      }
      __syncthreads();
      const int x = tid >> 2, c8 = tid & 3;
#pragma unroll
      for (int pp = 0; pp < 4; ++pp) {
        uint4 d = *(const uint4*)&lds[(pp * 64 + x) * 40 + c8 * 8];
        *(uint4*)&((u16*)out_)[((size_t)(((yb + pp) << 9) + xb + x)) * 64 +
                               mp * 32 + c8 * 8] = d;
      }
    }
  } else {
    // fp32 out (+res add): four phases of 16 ch. LDS view [4y][64x][20] f32
    // (row pad 20 -> 80 B: 16B-aligned rows, <=2-way banks).
    float* lf = (float*)lds;
#pragma unroll
    for (int mf = 0; mf < 4; ++mf) {
      __syncthreads();
      const float4 bv = *(const float4*)&bias[mf * 16 + kg * 4];
#pragma unroll
      for (int nf = 0; nf < 4; ++nf) {
        float4 t;
        t.x = acc[mf][nf][0] + bv.x;
        t.y = acc[mf][nf][1] + bv.y;
        t.z = acc[mf][nf][2] + bv.z;
        t.w = acc[mf][nf][3] + bv.w;
        *(float4*)&lf[(wv * 64 + nf * 16 + n) * 20 + kg * 4] = t;
      }
      __syncthreads();
      const int x = tid >> 2, c4 = tid & 3;
#pragma unroll
      for (int pp = 0; pp < 4; ++pp) {
        float4 d = *(const float4*)&lf[(pp * 64 + x) * 20 + c4 * 4];
        const size_t gg = ((size_t)(((yb + pp) << 9) + xb + x)) * 64 +
                          mf * 16 + c4 * 4;
        if (ADDRES) {
          float4 rr = *(const float4*)&res[gg];
          d.x += rr.x; d.y += rr.y; d.z += rr.z; d.w += rr.w;
        }
        if (RELU) {
          d.x = fmaxf(d.x, 0.f); d.y = fmaxf(d.y, 0.f);
          d.z = fmaxf(d.z, 0.f); d.w = fmaxf(d.w, 0.f);
        }
        *(float4*)&((float*)out_)[gg] = d;
      }
    }
  }
}

// ---------------------------------------------------------------------------
// conv_out: 64 -> 1, fp32 NHWC in (float4 loads), fp32 plane out.
// ---------------------------------------------------------------------------
__global__ __launch_bounds__(256) void conv_out_kernel(
    const float* __restrict__ in, const float* __restrict__ w,
    const float* __restrict__ b, float* __restrict__ out) {
  const int p = blockIdx.x * 256 + threadIdx.x;
  const int gx = p & (NX - 1), gy = p >> 9;
  float a = b[0];
#pragma unroll
  for (int ty = 0; ty < 3; ++ty) {
#pragma unroll
    for (int tx = 0; tx < 3; ++tx) {
      const int yy = gy + ty - 1, xx = gx + tx - 1;
      if ((unsigned)yy < 512u && (unsigned)xx < 512u) {
        const float4* q = (const float4*)(in + ((size_t)((yy << 9) + xx)) * 64);
        const int tap = ty * 3 + tx;
#pragma unroll
        for (int i = 0; i < 16; ++i) {
          float4 d = q[i];
          a = fmaf(d.x, w[(i * 4 + 0) * 9 + tap], a);
          a = fmaf(d.y, w[(i * 4 + 1) * 9 + tap], a);
          a = fmaf(d.z, w[(i * 4 + 2) * 9 + tap], a);
          a = fmaf(d.w, w[(i * 4 + 3) * 9 + tap], a);
        }
      }
    }
  }
  out[p] = a;
}

// ---------------------------------------------------------------------------
extern "C" void kernel_launch(void* const* d_in, const int* in_sizes, int n_in,
                              void* d_out, int out_size, void* d_ws,
                              size_t ws_size, hipStream_t stream) {
  const float* x      = (const float*)d_in[0];
  const int*   indices= (const int*)d_in[1];
  const float* w1     = (const float*)d_in[2];
  const float* b1     = (const float*)d_in[3];
  const float* w2     = (const float*)d_in[4];
  const float* b2     = (const float*)d_in[5];
  const float* cin_w  = (const float*)d_in[6];
  const float* cin_b  = (const float*)d_in[7];
  const float* bw1    = (const float*)d_in[8];
  const float* bb1    = (const float*)d_in[9];
  const float* bw2    = (const float*)d_in[10];
  const float* bb2    = (const float*)d_in[11];
  const float* cout_w = (const float*)d_in[12];
  const float* cout_b = (const float*)d_in[13];

  float* ws   = (float*)d_ws;
  float* h1   = ws;                      // 360*736 f32
  float* h2   = h1 + VIEWS * NDET;       // 360*736 f32
  float* img  = h2 + VIEWS * NDET;       // NPIX f32 (plane)
  float* yf   = img + NPIX;              // 64*NPIX f32 NHWC (residual stream)
  u16*  zb    = (u16*)(yf + (size_t)64 * NPIX);  // 64*NPIX bf16 NHWC
  u16*  wAll  = zb + (size_t)64 * NPIX;  // 22*64*576 bf16 (step,mf layout)

  prep_weights_kernel<<<(22 * 36864 + 255) / 256, 256, 0, stream>>>(bw1, bw2,
                                                                    wAll);
  linear_relu4_kernel<<<VIEWS / 4, 256, 0, stream>>>(x, w1, b1, h1);
  linear_relu4_kernel<<<VIEWS / 4, 256, 0, stream>>>(h1, w2, b2, h2);
  backproj_kernel<<<NPIX / 256, 256, 0, stream>>>(h2, indices, img);
  conv_in_kernel<<<NPIX / 256, 256, 0, stream>>>(img, cin_w, cin_b, yf);

  for (int i = 0; i < 11; ++i) {
    conv64_mfma<0, 1, 1, 0><<<1024, 256, 0, stream>>>(
        yf, wAll + i * 36864, bb1 + i * 64, nullptr, zb);
    conv64_mfma<1, 0, 1, 1><<<1024, 256, 0, stream>>>(
        zb, wAll + (11 + i) * 36864, bb2 + i * 64, yf, yf);
  }
  conv_out_kernel<<<NPIX / 256, 256, 0, stream>>>(yf, cout_w, cout_b,
                                                  (float*)d_out);
}